// Round 1
// baseline (2136.683 us; speedup 1.0000x reference)
//
#include <hip/hip_runtime.h>
#include <math.h>

#define NN 50000
#define EE 1600000
#define FIN 32
#define HID_ 128
#define ED_ 16
#define GG 512
#define MH_ 512
#define MO_ 512

// ---------------- CSR build ----------------

__global__ void hist_kernel(const int* __restrict__ dst, int* __restrict__ cnt) {
  int e = blockIdx.x * 256 + threadIdx.x;
  if (e < EE) atomicAdd(&cnt[dst[e]], 1);
}

__global__ __launch_bounds__(256) void scan1_kernel(const int* __restrict__ in, int n,
                                                    int* __restrict__ out,
                                                    int* __restrict__ bsums) {
  int chunk = blockIdx.x;
  int base = chunk * 1024;
  int t = threadIdx.x;
  int idx = base + t * 4;
  int v0 = (idx + 0 < n) ? in[idx + 0] : 0;
  int v1 = (idx + 1 < n) ? in[idx + 1] : 0;
  int v2 = (idx + 2 < n) ? in[idx + 2] : 0;
  int v3 = (idx + 3 < n) ? in[idx + 3] : 0;
  int ts = v0 + v1 + v2 + v3;
  int lane = t & 63, w = t >> 6;
  int s = ts;
#pragma unroll
  for (int off = 1; off < 64; off <<= 1) {
    int o = __shfl_up(s, off);
    if (lane >= off) s += o;
  }
  __shared__ int wsum[4];
  if (lane == 63) wsum[w] = s;
  __syncthreads();
  int woff = 0;
  for (int i = 0; i < w; i++) woff += wsum[i];
  int excl = woff + s - ts;  // exclusive prefix for this thread's first elem
  int run = excl;
  run += v0; if (idx + 0 < n) out[idx + 0] = run;
  run += v1; if (idx + 1 < n) out[idx + 1] = run;
  run += v2; if (idx + 2 < n) out[idx + 2] = run;
  run += v3; if (idx + 3 < n) out[idx + 3] = run;
  if (t == 255) bsums[chunk] = woff + s;
}

__global__ void scan_add_kernel(int* __restrict__ rowptr, const int* __restrict__ bscan, int n) {
  int i = blockIdx.x * 256 + threadIdx.x;
  if (i == 0) rowptr[0] = 0;
  if (i < n) {
    int chunk = i >> 10;
    if (chunk > 0) rowptr[1 + i] += bscan[chunk - 1];
  }
}

__global__ void scatter_kernel(const int* __restrict__ src, const int* __restrict__ dst,
                               const int* __restrict__ rowptr, int* __restrict__ fill,
                               int* __restrict__ csr_src, int* __restrict__ csr_eid) {
  int e = blockIdx.x * 256 + threadIdx.x;
  if (e >= EE) return;
  int v = dst[e];
  int pos = rowptr[v] + atomicAdd(&fill[v], 1);
  csr_src[pos] = src[e];
  csr_eid[pos] = e;
}

// loop_attr[v] = mean of incoming edge_attr (0 if no incoming edges)
__global__ __launch_bounds__(256) void loopattr_kernel(const int* __restrict__ rowptr,
                                                       const int* __restrict__ csr_eid,
                                                       const float* __restrict__ ea,
                                                       float* __restrict__ la) {
  int wid = threadIdx.x >> 6, lane = threadIdx.x & 63;
  int v = blockIdx.x * 4 + wid;
  if (v >= NN || lane >= 16) return;
  int s = rowptr[v], e = rowptr[v + 1];
  float acc = 0.f;
  for (int j = s; j < e; j++) acc += ea[csr_eid[j] * 16 + lane];
  la[v * 16 + lane] = (e > s) ? acc / (float)(e - s) : 0.f;
}

// ---------------- node linear transforms: xl = h@Wl+bl, xr = h@Wr+br ----------------

template <int F>
__global__ __launch_bounds__(256) void node_transform(const float* __restrict__ h,
                                                      const float* __restrict__ Wlm,
                                                      const float* __restrict__ blm,
                                                      const float* __restrict__ Wrm,
                                                      const float* __restrict__ brm,
                                                      float* __restrict__ xl,
                                                      float* __restrict__ xr, int nnodes) {
  __shared__ float hs[32 * F];
  int v0 = blockIdx.x * 32;
  int t = threadIdx.x;
  for (int idx = t; idx < 32 * F; idx += 256) {
    int g = v0 * F + idx;
    hs[idx] = (g < nnodes * F) ? h[g] : 0.f;
  }
  __syncthreads();
  int cc = t & 127;
  bool isL = t < 128;
  const float* W = isL ? Wlm : Wrm;
  float acc[32];
#pragma unroll
  for (int i = 0; i < 32; i++) acc[i] = 0.f;
  for (int k = 0; k < F; k++) {
    float w = W[k * 128 + cc];
#pragma unroll
    for (int i = 0; i < 32; i++) acc[i] += hs[i * F + k] * w;
  }
  float b = isL ? blm[cc] : brm[cc];
  float* dstp = isL ? xl : xr;
  int nb = nnodes - v0; if (nb > 32) nb = 32;
  for (int i = 0; i < nb; i++) dstp[(v0 + i) * 128 + cc] = acc[i] + b;
}

// ---------------- GATv2 edge scoring + online-softmax aggregation ----------------
// One wave per destination node. Lane l owns channels c0=l, c1=64+l.
// Head of c0 = l>>4 (0..3); head of c1 = 4+(l>>4).

__global__ __launch_bounds__(256) void gat_aggregate(
    const float* __restrict__ xl, const float* __restrict__ xr,
    const int* __restrict__ rowptr, const int* __restrict__ csr_src,
    const int* __restrict__ csr_eid, const float* __restrict__ ea,
    const float* __restrict__ la, const float* __restrict__ We,
    const float* __restrict__ att, const float* __restrict__ bias,
    float* __restrict__ hout, int relu) {
  int wid = threadIdx.x >> 6, lane = threadIdx.x & 63;
  int v = blockIdx.x * 4 + wid;
  if (v >= NN) return;
  int c0 = lane, c1 = 64 + lane;
  // hoist per-lane We columns (loop-invariant)
  float wec0[16], wec1[16];
#pragma unroll
  for (int k = 0; k < 16; k++) {
    wec0[k] = We[k * 128 + c0];
    wec1[k] = We[k * 128 + c1];
  }
  float a0 = att[c0], a1 = att[c1];
  float b0 = bias[c0], b1 = bias[c1];
  float xr0 = xr[v * 128 + c0], xr1 = xr[v * 128 + c1];
  float mx0 = -INFINITY, mx1 = -INFINITY;
  float den0 = 0.f, den1 = 0.f, acc0 = 0.f, acc1 = 0.f;
  int start = rowptr[v], end = rowptr[v + 1];
  for (int j = start - 1; j < end; ++j) {
    int u;
    const float4* eap;
    if (j < start) {  // self loop
      u = v;
      eap = (const float4*)(la + v * 16);
    } else {
      u = csr_src[j];
      int eid = csr_eid[j];
      eap = (const float4*)(ea + eid * 16);
    }
    float4 q0 = eap[0], q1 = eap[1], q2 = eap[2], q3 = eap[3];
    float ec[16] = {q0.x, q0.y, q0.z, q0.w, q1.x, q1.y, q1.z, q1.w,
                    q2.x, q2.y, q2.z, q2.w, q3.x, q3.y, q3.z, q3.w};
    float xlu0 = xl[u * 128 + c0], xlu1 = xl[u * 128 + c1];
    float ee0 = 0.f, ee1 = 0.f;
#pragma unroll
    for (int k = 0; k < 16; k++) {
      ee0 += ec[k] * wec0[k];
      ee1 += ec[k] * wec1[k];
    }
    float m0 = xlu0 + xr0 + ee0; m0 = m0 > 0.f ? m0 : 0.2f * m0;
    float m1 = xlu1 + xr1 + ee1; m1 = m1 > 0.f ? m1 : 0.2f * m1;
    float p0 = a0 * m0, p1 = a1 * m1;
#pragma unroll
    for (int off = 1; off < 16; off <<= 1) {
      p0 += __shfl_xor(p0, off);
      p1 += __shfl_xor(p1, off);
    }
    // online softmax update (per lane's two heads)
    float nm0 = fmaxf(mx0, p0);
    float f0 = __expf(mx0 - nm0);
    float w0 = __expf(p0 - nm0);
    den0 = den0 * f0 + w0;
    acc0 = acc0 * f0 + w0 * xlu0;
    mx0 = nm0;
    float nm1 = fmaxf(mx1, p1);
    float f1 = __expf(mx1 - nm1);
    float w1 = __expf(p1 - nm1);
    den1 = den1 * f1 + w1;
    acc1 = acc1 * f1 + w1 * xlu1;
    mx1 = nm1;
  }
  float o0 = acc0 / den0 + b0;
  float o1 = acc1 / den1 + b1;
  if (relu) { o0 = fmaxf(o0, 0.f); o1 = fmaxf(o1, 0.f); }
  hout[v * 128 + c0] = o0;
  hout[v * 128 + c1] = o1;
}

// ---------------- pooling + MLP ----------------

__global__ void gptr_kernel(const int* __restrict__ batch, int* __restrict__ gptr) {
  int g = blockIdx.x * 256 + threadIdx.x;
  if (g > GG) return;
  int lo = 0, hi = NN;
  while (lo < hi) {
    int mid = (lo + hi) >> 1;
    if (batch[mid] < g) lo = mid + 1; else hi = mid;
  }
  gptr[g] = lo;
}

__global__ void pool_kernel(const float* __restrict__ h, const int* __restrict__ gptr,
                            float* __restrict__ gp) {
  int gi = blockIdx.x;
  int c = threadIdx.x;  // 128
  int s = gptr[gi], e = gptr[gi + 1];
  float acc = 0.f;
  for (int v = s; v < e; v++) acc += h[v * 128 + c];
  gp[gi * 128 + c] = acc;
}

__global__ __launch_bounds__(256) void mlp1_kernel(const float* __restrict__ gp,
                                                   const float* __restrict__ mW1,
                                                   const float* __restrict__ mb1,
                                                   const float* __restrict__ lng,
                                                   const float* __restrict__ lnb,
                                                   float* __restrict__ z) {
  int row = blockIdx.x;
  int t = threadIdx.x;
  __shared__ float gs[128];
  if (t < 128) gs[t] = gp[row * 128 + t];
  __syncthreads();
  int c0 = t, c1 = t + 256;
  float z0 = 0.f, z1 = 0.f;
  for (int k = 0; k < 128; k++) {
    float gk = gs[k];
    z0 += gk * mW1[k * 512 + c0];
    z1 += gk * mW1[k * 512 + c1];
  }
  z0 += mb1[c0]; z1 += mb1[c1];
  z0 = fmaxf(z0, 0.f); z1 = fmaxf(z1, 0.f);
  float s = z0 + z1, q = z0 * z0 + z1 * z1;
#pragma unroll
  for (int off = 32; off > 0; off >>= 1) {
    s += __shfl_xor(s, off);
    q += __shfl_xor(q, off);
  }
  __shared__ float red[8];
  int lane = t & 63, w = t >> 6;
  if (lane == 0) { red[w] = s; red[4 + w] = q; }
  __syncthreads();
  float S = red[0] + red[1] + red[2] + red[3];
  float Q = red[4] + red[5] + red[6] + red[7];
  float mu = S / 512.f;
  float var = Q / 512.f - mu * mu;
  float inv = 1.f / sqrtf(var + 1e-5f);
  z[row * 512 + c0] = (z0 - mu) * inv * lng[c0] + lnb[c0];
  z[row * 512 + c1] = (z1 - mu) * inv * lng[c1] + lnb[c1];
}

__global__ __launch_bounds__(256) void mlp2_kernel(const float* __restrict__ z,
                                                   const float* __restrict__ mW2,
                                                   const float* __restrict__ mb2,
                                                   float* __restrict__ out) {
  int row = blockIdx.x;
  int t = threadIdx.x;
  __shared__ float zs[512];
  for (int i = t; i < 512; i += 256) zs[i] = z[row * 512 + i];
  __syncthreads();
  int c0 = t, c1 = t + 256;
  float o0 = 0.f, o1 = 0.f;
  for (int k = 0; k < 512; k++) {
    float zk = zs[k];
    o0 += zk * mW2[k * 512 + c0];
    o1 += zk * mW2[k * 512 + c1];
  }
  out[row * 512 + c0] = o0 + mb2[c0];
  out[row * 512 + c1] = o1 + mb2[c1];
}

// ---------------- launcher ----------------

extern "C" void kernel_launch(void* const* d_in, const int* in_sizes, int n_in,
                              void* d_out, int out_size, void* d_ws, size_t ws_size,
                              hipStream_t stream) {
  const float* x = (const float*)d_in[0];
  const int* ei = (const int*)d_in[1];
  const int* srcE = ei;
  const int* dstE = ei + EE;
  const float* ea = (const float*)d_in[2];
  const int* batch = (const int*)d_in[3];
  const float* Wl[3] = {(const float*)d_in[4], (const float*)d_in[11], (const float*)d_in[18]};
  const float* bl[3] = {(const float*)d_in[5], (const float*)d_in[12], (const float*)d_in[19]};
  const float* Wr[3] = {(const float*)d_in[6], (const float*)d_in[13], (const float*)d_in[20]};
  const float* br[3] = {(const float*)d_in[7], (const float*)d_in[14], (const float*)d_in[21]};
  const float* Wek[3] = {(const float*)d_in[8], (const float*)d_in[15], (const float*)d_in[22]};
  const float* attk[3] = {(const float*)d_in[9], (const float*)d_in[16], (const float*)d_in[23]};
  const float* bk[3] = {(const float*)d_in[10], (const float*)d_in[17], (const float*)d_in[24]};
  const float* mW1 = (const float*)d_in[25];
  const float* mb1 = (const float*)d_in[26];
  const float* lng = (const float*)d_in[27];
  const float* lnb = (const float*)d_in[28];
  const float* mW2 = (const float*)d_in[29];
  const float* mb2 = (const float*)d_in[30];
  float* outp = (float*)d_out;

  char* W = (char*)d_ws;
  size_t off = 0;
  auto take = [&](size_t b) -> void* {
    void* p = W + off;
    off += (b + 255) & ~(size_t)255;
    return p;
  };
  int* cnt = (int*)take(NN * 4);  // doubles as fill cursor
  int* rowptr = (int*)take((NN + 1) * 4);
  int* bsums = (int*)take(64 * 4);
  int* bscan = (int*)take(64 * 4);
  int* dummy = (int*)take(64 * 4);
  int* csr_src = (int*)take((size_t)EE * 4);
  int* csr_eid = (int*)take((size_t)EE * 4);
  float* la = (float*)take((size_t)NN * 16 * 4);
  float* xl = (float*)take((size_t)NN * HID_ * 4);
  float* xr = (float*)take((size_t)NN * HID_ * 4);
  float* hbuf = (float*)take((size_t)NN * HID_ * 4);
  int* gptr = (int*)take((GG + 1) * 4);
  float* gpool = (float*)take((size_t)GG * HID_ * 4);
  float* z = (float*)take((size_t)GG * MH_ * 4);
  (void)ws_size; (void)n_in; (void)in_sizes; (void)out_size;

  // CSR build
  hipMemsetAsync(cnt, 0, NN * 4, stream);
  hist_kernel<<<(EE + 255) / 256, 256, 0, stream>>>(dstE, cnt);
  scan1_kernel<<<49, 256, 0, stream>>>(cnt, NN, rowptr + 1, bsums);
  scan1_kernel<<<1, 256, 0, stream>>>(bsums, 49, bscan, dummy);
  scan_add_kernel<<<(NN + 255) / 256, 256, 0, stream>>>(rowptr, bscan, NN);
  hipMemsetAsync(cnt, 0, NN * 4, stream);
  scatter_kernel<<<(EE + 255) / 256, 256, 0, stream>>>(srcE, dstE, rowptr, cnt, csr_src, csr_eid);
  loopattr_kernel<<<(NN + 3) / 4, 256, 0, stream>>>(rowptr, csr_eid, ea, la);

  // 3 GATv2 layers
  for (int l = 0; l < 3; l++) {
    if (l == 0)
      node_transform<FIN><<<(NN + 31) / 32, 256, 0, stream>>>(x, Wl[0], bl[0], Wr[0], br[0],
                                                              xl, xr, NN);
    else
      node_transform<HID_><<<(NN + 31) / 32, 256, 0, stream>>>(hbuf, Wl[l], bl[l], Wr[l], br[l],
                                                               xl, xr, NN);
    gat_aggregate<<<(NN + 3) / 4, 256, 0, stream>>>(xl, xr, rowptr, csr_src, csr_eid, ea, la,
                                                    Wek[l], attk[l], bk[l], hbuf,
                                                    (l < 2) ? 1 : 0);
  }

  // pooling + MLP head
  gptr_kernel<<<3, 256, 0, stream>>>(batch, gptr);
  pool_kernel<<<GG, 128, 0, stream>>>(hbuf, gptr, gpool);
  mlp1_kernel<<<GG, 256, 0, stream>>>(gpool, mW1, mb1, lng, lnb, z);
  mlp2_kernel<<<GG, 256, 0, stream>>>(z, mW2, mb2, outp);
}

// Round 2
// 1017.607 us; speedup vs baseline: 2.0997x; 2.0997x over previous
//
#include <hip/hip_runtime.h>
#include <math.h>

#define NN 50000
#define EE 1600000
#define FIN 32
#define HID_ 128
#define ED_ 16
#define GG 512
#define MH_ 512
#define MO_ 512

#if __has_builtin(__builtin_amdgcn_exp2f)
#define EXP2(x) __builtin_amdgcn_exp2f(x)
#else
#define EXP2(x) exp2f(x)
#endif

// ---------------- CSR build ----------------

__global__ void hist_kernel(const int* __restrict__ dst, int* __restrict__ cnt) {
  int e = blockIdx.x * 256 + threadIdx.x;
  if (e < EE) atomicAdd(&cnt[dst[e]], 1);
}

__global__ __launch_bounds__(256) void scan1_kernel(const int* __restrict__ in, int n,
                                                    int* __restrict__ out,
                                                    int* __restrict__ bsums) {
  int chunk = blockIdx.x;
  int base = chunk * 1024;
  int t = threadIdx.x;
  int idx = base + t * 4;
  int v0 = (idx + 0 < n) ? in[idx + 0] : 0;
  int v1 = (idx + 1 < n) ? in[idx + 1] : 0;
  int v2 = (idx + 2 < n) ? in[idx + 2] : 0;
  int v3 = (idx + 3 < n) ? in[idx + 3] : 0;
  int ts = v0 + v1 + v2 + v3;
  int lane = t & 63, w = t >> 6;
  int s = ts;
#pragma unroll
  for (int off = 1; off < 64; off <<= 1) {
    int o = __shfl_up(s, off);
    if (lane >= off) s += o;
  }
  __shared__ int wsum[4];
  if (lane == 63) wsum[w] = s;
  __syncthreads();
  int woff = 0;
  for (int i = 0; i < w; i++) woff += wsum[i];
  int excl = woff + s - ts;
  int run = excl;
  run += v0; if (idx + 0 < n) out[idx + 0] = run;
  run += v1; if (idx + 1 < n) out[idx + 1] = run;
  run += v2; if (idx + 2 < n) out[idx + 2] = run;
  run += v3; if (idx + 3 < n) out[idx + 3] = run;
  if (t == 255) bsums[chunk] = woff + s;
}

__global__ void scan_add_kernel(int* __restrict__ rowptr, const int* __restrict__ bscan, int n) {
  int i = blockIdx.x * 256 + threadIdx.x;
  if (i == 0) rowptr[0] = 0;
  if (i < n) {
    int chunk = i >> 10;
    if (chunk > 0) rowptr[1 + i] += bscan[chunk - 1];
  }
}

__global__ void scatter_kernel(const int* __restrict__ src, const int* __restrict__ dst,
                               const int* __restrict__ rowptr, int* __restrict__ fill,
                               int2* __restrict__ csr) {
  int e = blockIdx.x * 256 + threadIdx.x;
  if (e >= EE) return;
  int v = dst[e];
  int pos = rowptr[v] + atomicAdd(&fill[v], 1);
  csr[pos] = make_int2(src[e], e);
}

// loop_attr[v] = mean of incoming edge_attr (0 if no incoming edges)
__global__ __launch_bounds__(256) void loopattr_kernel(const int* __restrict__ rowptr,
                                                       const int2* __restrict__ csr,
                                                       const float* __restrict__ ea,
                                                       float* __restrict__ la) {
  int wid = threadIdx.x >> 6, lane = threadIdx.x & 63;
  int v = __builtin_amdgcn_readfirstlane(blockIdx.x * 4 + wid);
  if (v >= NN) return;
  int s = __builtin_amdgcn_readfirstlane(rowptr[v]);
  int e = __builtin_amdgcn_readfirstlane(rowptr[v + 1]);
  int k = lane >> 4;   // 4 edges in flight
  int d = lane & 15;
  float acc = 0.f;
  for (int j = s + k; j < e; j += 4) acc += ea[(size_t)csr[j].y * 16 + d];
  acc += __shfl_xor(acc, 16);
  acc += __shfl_xor(acc, 32);
  if (lane < 16) la[(size_t)v * 16 + d] = (e > s) ? acc / (float)(e - s) : 0.f;
}

// ---------------- node linear transforms: xl = h@Wl+bl, xr = h@Wr+br ----------------
// LDS holds the 32-node tile TRANSPOSED [k][i] so inner reads are ds_read_b128 broadcasts.

template <int F>
__global__ __launch_bounds__(256) void node_transform(const float* __restrict__ h,
                                                      const float* __restrict__ Wlm,
                                                      const float* __restrict__ blm,
                                                      const float* __restrict__ Wrm,
                                                      const float* __restrict__ brm,
                                                      float* __restrict__ xl,
                                                      float* __restrict__ xr, int nnodes) {
  __shared__ float hs[F * 32];  // [k][i]
  int v0 = blockIdx.x * 32;
  int t = threadIdx.x;
  for (int idx = t; idx < 32 * F; idx += 256) {
    int i = idx / F, k = idx - i * F;
    float val = (v0 + i < nnodes) ? h[(size_t)(v0 + i) * F + k] : 0.f;
    hs[k * 32 + i] = val;
  }
  __syncthreads();
  int cc = t & 127;
  bool isL = t < 128;
  const float* W = isL ? Wlm : Wrm;
  float4 acc[8];
#pragma unroll
  for (int q = 0; q < 8; q++) acc[q] = make_float4(0.f, 0.f, 0.f, 0.f);
  const float4* hs4 = (const float4*)hs;
  for (int k = 0; k < F; k++) {
    float w = W[k * 128 + cc];
#pragma unroll
    for (int q = 0; q < 8; q++) {
      float4 hv = hs4[k * 8 + q];
      acc[q].x = fmaf(hv.x, w, acc[q].x);
      acc[q].y = fmaf(hv.y, w, acc[q].y);
      acc[q].z = fmaf(hv.z, w, acc[q].z);
      acc[q].w = fmaf(hv.w, w, acc[q].w);
    }
  }
  float b = isL ? blm[cc] : brm[cc];
  float* dstp = isL ? xl : xr;
  int nb = nnodes - v0; if (nb > 32) nb = 32;
#pragma unroll
  for (int q = 0; q < 8; q++) {
    if (4 * q + 0 < nb) dstp[(size_t)(v0 + 4 * q + 0) * 128 + cc] = acc[q].x + b;
    if (4 * q + 1 < nb) dstp[(size_t)(v0 + 4 * q + 1) * 128 + cc] = acc[q].y + b;
    if (4 * q + 2 < nb) dstp[(size_t)(v0 + 4 * q + 2) * 128 + cc] = acc[q].z + b;
    if (4 * q + 3 < nb) dstp[(size_t)(v0 + 4 * q + 3) * 128 + cc] = acc[q].w + b;
  }
}

// ---------------- GATv2 edge scoring + online-softmax aggregation ----------------
// One wave per destination node (v scalarized via readfirstlane so all per-edge
// metadata loads become scalar). Lane l owns channels c0=l, c1=64+l.

__global__ __launch_bounds__(256) void gat_aggregate(
    const float* __restrict__ xl, const float* __restrict__ xr,
    const int* __restrict__ rowptr, const int2* __restrict__ csr,
    const float* __restrict__ ea, const float* __restrict__ la,
    const float* __restrict__ We, const float* __restrict__ att,
    const float* __restrict__ bias, float* __restrict__ hout, int relu) {
  int wid = threadIdx.x >> 6, lane = threadIdx.x & 63;
  int v = __builtin_amdgcn_readfirstlane(blockIdx.x * 4 + wid);
  if (v >= NN) return;
  int c0 = lane, c1 = 64 + lane;
  float wec0[16], wec1[16];
#pragma unroll
  for (int k = 0; k < 16; k++) {
    wec0[k] = We[k * 128 + c0];
    wec1[k] = We[k * 128 + c1];
  }
  const float L2E = 1.44269504088896340736f;
  float a0 = att[c0] * L2E, a1 = att[c1] * L2E;
  float xr0 = xr[(size_t)v * 128 + c0], xr1 = xr[(size_t)v * 128 + c1];

  auto score = [&](int u, const float* eaP,
                   float& xlu0, float& xlu1, float& p0, float& p1) {
    float ec[16];
#pragma unroll
    for (int k = 0; k < 4; k++) {
      float4 q = ((const float4*)eaP)[k];
      ec[4 * k + 0] = q.x; ec[4 * k + 1] = q.y;
      ec[4 * k + 2] = q.z; ec[4 * k + 3] = q.w;
    }
    const float* xlu = xl + (size_t)u * 128;
    xlu0 = xlu[c0]; xlu1 = xlu[c1];
    float m0 = xr0 + xlu0, m1 = xr1 + xlu1;
#pragma unroll
    for (int k = 0; k < 16; k++) {
      m0 = fmaf(ec[k], wec0[k], m0);
      m1 = fmaf(ec[k], wec1[k], m1);
    }
    m0 = fmaxf(m0, 0.2f * m0);          // LeakyReLU
    m1 = fmaxf(m1, 0.2f * m1);
    p0 = a0 * m0; p1 = a1 * m1;
#pragma unroll
    for (int off = 1; off < 16; off <<= 1) {
      p0 += __shfl_xor(p0, off);
      p1 += __shfl_xor(p1, off);
    }
  };

  // self-loop initializes the online softmax (exp2 domain)
  float mx0, mx1, den0 = 1.f, den1 = 1.f, acc0, acc1;
  {
    float xs0, xs1, p0, p1;
    score(v, la + (size_t)v * 16, xs0, xs1, p0, p1);
    mx0 = p0; mx1 = p1; acc0 = xs0; acc1 = xs1;
  }
  int start = __builtin_amdgcn_readfirstlane(rowptr[v]);
  int end = __builtin_amdgcn_readfirstlane(rowptr[v + 1]);
  int j = start;
  for (; j + 1 < end; j += 2) {
    int2 ep0 = csr[j], ep1 = csr[j + 1];
    float xa0, xa1, pa0, pa1, xb0, xb1, pb0, pb1;
    score(ep0.x, ea + (size_t)ep0.y * 16, xa0, xa1, pa0, pa1);
    score(ep1.x, ea + (size_t)ep1.y * 16, xb0, xb1, pb0, pb1);
    float nm0 = fmaxf(mx0, fmaxf(pa0, pb0));
    float f0 = EXP2(mx0 - nm0), wa0 = EXP2(pa0 - nm0), wb0 = EXP2(pb0 - nm0);
    den0 = fmaf(den0, f0, wa0 + wb0);
    acc0 = fmaf(acc0, f0, fmaf(wa0, xa0, wb0 * xb0));
    mx0 = nm0;
    float nm1 = fmaxf(mx1, fmaxf(pa1, pb1));
    float f1 = EXP2(mx1 - nm1), wa1 = EXP2(pa1 - nm1), wb1 = EXP2(pb1 - nm1);
    den1 = fmaf(den1, f1, wa1 + wb1);
    acc1 = fmaf(acc1, f1, fmaf(wa1, xa1, wb1 * xb1));
    mx1 = nm1;
  }
  if (j < end) {
    int2 ep0 = csr[j];
    float xa0, xa1, pa0, pa1;
    score(ep0.x, ea + (size_t)ep0.y * 16, xa0, xa1, pa0, pa1);
    float nm0 = fmaxf(mx0, pa0);
    float f0 = EXP2(mx0 - nm0), wa0 = EXP2(pa0 - nm0);
    den0 = fmaf(den0, f0, wa0);
    acc0 = fmaf(acc0, f0, wa0 * xa0);
    float nm1 = fmaxf(mx1, pa1);
    float f1 = EXP2(mx1 - nm1), wa1 = EXP2(pa1 - nm1);
    den1 = fmaf(den1, f1, wa1);
    acc1 = fmaf(acc1, f1, wa1 * xa1);
  }
  float o0 = acc0 / den0 + bias[c0];
  float o1 = acc1 / den1 + bias[c1];
  if (relu) { o0 = fmaxf(o0, 0.f); o1 = fmaxf(o1, 0.f); }
  hout[(size_t)v * 128 + c0] = o0;
  hout[(size_t)v * 128 + c1] = o1;
}

// ---------------- pooling + MLP ----------------

__global__ void gptr_kernel(const int* __restrict__ batch, int* __restrict__ gptr) {
  int g = blockIdx.x * 256 + threadIdx.x;
  if (g > GG) return;
  int lo = 0, hi = NN;
  while (lo < hi) {
    int mid = (lo + hi) >> 1;
    if (batch[mid] < g) lo = mid + 1; else hi = mid;
  }
  gptr[g] = lo;
}

__global__ void pool_kernel(const float* __restrict__ h, const int* __restrict__ gptr,
                            float* __restrict__ gp) {
  int gi = blockIdx.x;
  int c = threadIdx.x;  // 128
  int s = gptr[gi], e = gptr[gi + 1];
  float acc = 0.f;
  for (int v = s; v < e; v++) acc += h[(size_t)v * 128 + c];
  gp[gi * 128 + c] = acc;
}

__global__ __launch_bounds__(256) void mlp1_kernel(const float* __restrict__ gp,
                                                   const float* __restrict__ mW1,
                                                   const float* __restrict__ mb1,
                                                   const float* __restrict__ lng,
                                                   const float* __restrict__ lnb,
                                                   float* __restrict__ z) {
  int row = blockIdx.x;
  int t = threadIdx.x;
  __shared__ float gs[128];
  if (t < 128) gs[t] = gp[row * 128 + t];
  __syncthreads();
  int c0 = t, c1 = t + 256;
  float z0 = 0.f, z1 = 0.f;
  for (int k = 0; k < 128; k++) {
    float gk = gs[k];
    z0 = fmaf(gk, mW1[k * 512 + c0], z0);
    z1 = fmaf(gk, mW1[k * 512 + c1], z1);
  }
  z0 += mb1[c0]; z1 += mb1[c1];
  z0 = fmaxf(z0, 0.f); z1 = fmaxf(z1, 0.f);
  float s = z0 + z1, q = z0 * z0 + z1 * z1;
#pragma unroll
  for (int off = 32; off > 0; off >>= 1) {
    s += __shfl_xor(s, off);
    q += __shfl_xor(q, off);
  }
  __shared__ float red[8];
  int lane = t & 63, w = t >> 6;
  if (lane == 0) { red[w] = s; red[4 + w] = q; }
  __syncthreads();
  float S = red[0] + red[1] + red[2] + red[3];
  float Q = red[4] + red[5] + red[6] + red[7];
  float mu = S / 512.f;
  float var = Q / 512.f - mu * mu;
  float inv = 1.f / sqrtf(var + 1e-5f);
  z[row * 512 + c0] = (z0 - mu) * inv * lng[c0] + lnb[c0];
  z[row * 512 + c1] = (z1 - mu) * inv * lng[c1] + lnb[c1];
}

__global__ __launch_bounds__(256) void mlp2_kernel(const float* __restrict__ z,
                                                   const float* __restrict__ mW2,
                                                   const float* __restrict__ mb2,
                                                   float* __restrict__ out) {
  int row = blockIdx.x;
  int t = threadIdx.x;
  __shared__ float zs[512];
  for (int i = t; i < 512; i += 256) zs[i] = z[row * 512 + i];
  __syncthreads();
  int c0 = t, c1 = t + 256;
  float o0 = 0.f, o1 = 0.f;
  for (int k = 0; k < 512; k++) {
    float zk = zs[k];
    o0 = fmaf(zk, mW2[k * 512 + c0], o0);
    o1 = fmaf(zk, mW2[k * 512 + c1], o1);
  }
  out[row * 512 + c0] = o0 + mb2[c0];
  out[row * 512 + c1] = o1 + mb2[c1];
}

// ---------------- launcher ----------------

extern "C" void kernel_launch(void* const* d_in, const int* in_sizes, int n_in,
                              void* d_out, int out_size, void* d_ws, size_t ws_size,
                              hipStream_t stream) {
  const float* x = (const float*)d_in[0];
  const int* ei = (const int*)d_in[1];
  const int* srcE = ei;
  const int* dstE = ei + EE;
  const float* ea = (const float*)d_in[2];
  const int* batch = (const int*)d_in[3];
  const float* Wl[3] = {(const float*)d_in[4], (const float*)d_in[11], (const float*)d_in[18]};
  const float* bl[3] = {(const float*)d_in[5], (const float*)d_in[12], (const float*)d_in[19]};
  const float* Wr[3] = {(const float*)d_in[6], (const float*)d_in[13], (const float*)d_in[20]};
  const float* br[3] = {(const float*)d_in[7], (const float*)d_in[14], (const float*)d_in[21]};
  const float* Wek[3] = {(const float*)d_in[8], (const float*)d_in[15], (const float*)d_in[22]};
  const float* attk[3] = {(const float*)d_in[9], (const float*)d_in[16], (const float*)d_in[23]};
  const float* bk[3] = {(const float*)d_in[10], (const float*)d_in[17], (const float*)d_in[24]};
  const float* mW1 = (const float*)d_in[25];
  const float* mb1 = (const float*)d_in[26];
  const float* lng = (const float*)d_in[27];
  const float* lnb = (const float*)d_in[28];
  const float* mW2 = (const float*)d_in[29];
  const float* mb2 = (const float*)d_in[30];
  float* outp = (float*)d_out;

  char* W = (char*)d_ws;
  size_t off = 0;
  auto take = [&](size_t b) -> void* {
    void* p = W + off;
    off += (b + 255) & ~(size_t)255;
    return p;
  };
  int* cnt = (int*)take(NN * 4);  // doubles as fill cursor
  int* rowptr = (int*)take((NN + 1) * 4);
  int* bsums = (int*)take(64 * 4);
  int* bscan = (int*)take(64 * 4);
  int* dummy = (int*)take(64 * 4);
  int2* csr = (int2*)take((size_t)EE * 8);
  float* la = (float*)take((size_t)NN * 16 * 4);
  float* xl = (float*)take((size_t)NN * HID_ * 4);
  float* xr = (float*)take((size_t)NN * HID_ * 4);
  float* hbuf = (float*)take((size_t)NN * HID_ * 4);
  int* gptr = (int*)take((GG + 1) * 4);
  float* gpool = (float*)take((size_t)GG * HID_ * 4);
  float* z = (float*)take((size_t)GG * MH_ * 4);
  (void)ws_size; (void)n_in; (void)in_sizes; (void)out_size;

  // CSR build
  hipMemsetAsync(cnt, 0, NN * 4, stream);
  hist_kernel<<<(EE + 255) / 256, 256, 0, stream>>>(dstE, cnt);
  scan1_kernel<<<49, 256, 0, stream>>>(cnt, NN, rowptr + 1, bsums);
  scan1_kernel<<<1, 256, 0, stream>>>(bsums, 49, bscan, dummy);
  scan_add_kernel<<<(NN + 255) / 256, 256, 0, stream>>>(rowptr, bscan, NN);
  hipMemsetAsync(cnt, 0, NN * 4, stream);
  scatter_kernel<<<(EE + 255) / 256, 256, 0, stream>>>(srcE, dstE, rowptr, cnt, csr);
  loopattr_kernel<<<(NN + 3) / 4, 256, 0, stream>>>(rowptr, csr, ea, la);

  // 3 GATv2 layers
  for (int l = 0; l < 3; l++) {
    if (l == 0)
      node_transform<FIN><<<(NN + 31) / 32, 256, 0, stream>>>(x, Wl[0], bl[0], Wr[0], br[0],
                                                              xl, xr, NN);
    else
      node_transform<HID_><<<(NN + 31) / 32, 256, 0, stream>>>(hbuf, Wl[l], bl[l], Wr[l], br[l],
                                                               xl, xr, NN);
    gat_aggregate<<<(NN + 3) / 4, 256, 0, stream>>>(xl, xr, rowptr, csr, ea, la,
                                                    Wek[l], attk[l], bk[l], hbuf,
                                                    (l < 2) ? 1 : 0);
  }

  // pooling + MLP head
  gptr_kernel<<<3, 256, 0, stream>>>(batch, gptr);
  pool_kernel<<<GG, 128, 0, stream>>>(hbuf, gptr, gpool);
  mlp1_kernel<<<GG, 256, 0, stream>>>(gpool, mW1, mb1, lng, lnb, z);
  mlp2_kernel<<<GG, 256, 0, stream>>>(z, mW2, mb2, outp);
}